// Round 3
// baseline (197.840 us; speedup 1.0000x reference)
//
#include <hip/hip_runtime.h>
#include <hip/hip_bf16.h>

// Problem dims (fixed by reference): B=512, Q=64, S=36, D=1024, SIM=256
#define BB 512
#define QQ 64
#define SS 36
#define DD 1024
#define SIM 256

typedef unsigned short u16x8 __attribute__((ext_vector_type(8)));
typedef __bf16 bf16x8 __attribute__((ext_vector_type(8)));
typedef float f32x4 __attribute__((ext_vector_type(4)));

__device__ __forceinline__ unsigned short f2bf(float f) {
  unsigned u = __float_as_uint(f);
  u += 0x7FFFu + ((u >> 16) & 1u);   // round-to-nearest-even
  return (unsigned short)(u >> 16);
}
__device__ __forceinline__ float bf2f(unsigned short h) {
  return __uint_as_float(((unsigned)h) << 16);
}

// ---------------------------------------------------------------------------
// K0: one-shot W (256x1024 f32) -> bf16 row-major copy in ws. L2-resident.
// ---------------------------------------------------------------------------
__global__ __launch_bounds__(256) void k0_w16(const float* __restrict__ W,
                                              unsigned short* __restrict__ W16) {
  int i = blockIdx.x * 256 + threadIdx.x;  // 65536 float4s
  float4 v = ((const float4*)W)[i];
  ushort4 p;
  p.x = f2bf(v.x); p.y = f2bf(v.y); p.z = f2bf(v.z); p.w = f2bf(v.w);
  ((ushort4*)W16)[i] = p;
}

// ---------------------------------------------------------------------------
// K1 (unchanged, at HBM roofline): per-batch scores = ctx . qm^T via MFMA,
// leaky -> l2norm over Q -> softmax over S -> probs (B,Q,S) f32 to ws.
// ---------------------------------------------------------------------------
__global__ __launch_bounds__(256) void k1_attn(
    const float* __restrict__ query, const float* __restrict__ context,
    const float* __restrict__ matrix, const int* __restrict__ smoothp,
    float* __restrict__ attn) {
  __shared__ __align__(16) char smem1[30464];
  unsigned short* qmL = (unsigned short*)smem1;            // [64][136]
  unsigned short* ctxL = (unsigned short*)(smem1 + 17408); // [48][136]
  float* sc = (float*)smem1;                               // [48][68] (after GEMM)

  const int t = threadIdx.x;
  const int bb = blockIdx.x;
  const int lane = t & 63, w = t >> 6;
  const int ml = lane & 15, kg = lane >> 4;
  const float smf = (float)smoothp[0];

  f32x4 acc[3];
#pragma unroll
  for (int mt = 0; mt < 3; ++mt) acc[mt] = (f32x4){0.f, 0.f, 0.f, 0.f};

  for (int ch = 0; ch < 8; ++ch) {
    const int d0 = ch * 128;
#pragma unroll
    for (int i = 0; i < 4; ++i) {
      int idx = t + 256 * i;
      int row = idx >> 4, c8 = idx & 15;
      const float4* gq = (const float4*)&query[((size_t)bb * QQ + row) * DD + d0 + c8 * 8];
      const float4* gm = (const float4*)&matrix[((size_t)bb * QQ + row) * DD + d0 + c8 * 8];
      float4 a0 = gq[0], a1 = gq[1], m0 = gm[0], m1 = gm[1];
      u16x8 pk;
      pk[0] = f2bf(a0.x * m0.x); pk[1] = f2bf(a0.y * m0.y);
      pk[2] = f2bf(a0.z * m0.z); pk[3] = f2bf(a0.w * m0.w);
      pk[4] = f2bf(a1.x * m1.x); pk[5] = f2bf(a1.y * m1.y);
      pk[6] = f2bf(a1.z * m1.z); pk[7] = f2bf(a1.w * m1.w);
      *(u16x8*)&qmL[row * 136 + c8 * 8] = pk;
    }
#pragma unroll
    for (int i = 0; i < 3; ++i) {
      int idx = t + 256 * i;
      int row = idx >> 4, c8 = idx & 15;
      u16x8 pk = (u16x8){0, 0, 0, 0, 0, 0, 0, 0};
      if (row < 36) {
        const float4* gc = (const float4*)&context[((size_t)bb * SS + row) * DD + d0 + c8 * 8];
        float4 a0 = gc[0], a1 = gc[1];
        pk[0] = f2bf(a0.x); pk[1] = f2bf(a0.y); pk[2] = f2bf(a0.z); pk[3] = f2bf(a0.w);
        pk[4] = f2bf(a1.x); pk[5] = f2bf(a1.y); pk[6] = f2bf(a1.z); pk[7] = f2bf(a1.w);
      }
      *(u16x8*)&ctxL[row * 136 + c8 * 8] = pk;
    }
    __syncthreads();
#pragma unroll
    for (int ks = 0; ks < 4; ++ks) {
      const int ko = ks * 32 + kg * 8;
      bf16x8 bfrag = __builtin_bit_cast(bf16x8, *(const u16x8*)&qmL[(w * 16 + ml) * 136 + ko]);
#pragma unroll
      for (int mt = 0; mt < 3; ++mt) {
        bf16x8 afrag =
            __builtin_bit_cast(bf16x8, *(const u16x8*)&ctxL[(mt * 16 + ml) * 136 + ko]);
        acc[mt] = __builtin_amdgcn_mfma_f32_16x16x32_bf16(afrag, bfrag, acc[mt], 0, 0, 0);
      }
    }
    __syncthreads();
  }

#pragma unroll
  for (int mt = 0; mt < 3; ++mt)
#pragma unroll
    for (int ii = 0; ii < 4; ++ii) {
      float v = acc[mt][ii];
      v = v > 0.f ? v : 0.1f * v;
      sc[(mt * 16 + kg * 4 + ii) * 68 + w * 16 + ml] = v;
    }
  __syncthreads();

  if (t < 36) {
    float ssum = 0.f;
    for (int qi = 0; qi < 64; ++qi) { float v = sc[t * 68 + qi]; ssum = fmaf(v, v, ssum); }
    float rn = 1.f / (sqrtf(ssum) + 1e-8f);
    for (int qi = 0; qi < 64; ++qi) sc[t * 68 + qi] *= rn;
  }
  __syncthreads();

  if (t < 64) {
    float mx = -1e30f;
    for (int s2 = 0; s2 < 36; ++s2) mx = fmaxf(mx, sc[s2 * 68 + t]);
    float sum = 0.f;
    float ev[36];
    for (int s2 = 0; s2 < 36; ++s2) {
      float e = __expf((sc[s2 * 68 + t] - mx) * smf);
      ev[s2] = e;
      sum += e;
    }
    float rs = 1.f / sum;
    size_t base = ((size_t)bb * QQ + t) * SS;
    for (int s2 = 0; s2 < 36; ++s2) attn[base + s2] = ev[s2] * rs;
  }
}

// ---------------------------------------------------------------------------
// K2 (restructured): per-batch, 512 thr (8 waves), 58.6 KB LDS, 2 blocks/CU.
//  G = C.C^T (MFMA, 48x48 pad, K=1024)        -> ||wc_q||^2 = p G p^T (VALU)
//  per 128-d chunk: wc = P.C (MFMA, K=48pad)  -> A = (q - wc*rn)^2 (regs)
//                   -> sim GEMM accumulate A.W16^T (MFMA, B-frags from global)
//  epilogue: +bias, l2norm over 256, store.
// LDS: P16[64][72] | Gf[48][52] | CTX union(ctxL[48][136], ctxT[128][72])
//      | A16[64][136] | bias | rn | rowsum = 58624 B.
// ---------------------------------------------------------------------------
template <bool USE_W16>
__global__ __launch_bounds__(512, 4) void k2_fused(
    const float* __restrict__ query, const float* __restrict__ context,
    const float* __restrict__ Wm, const float* __restrict__ bvec,
    const float* __restrict__ attn, const unsigned short* __restrict__ W16,
    float* __restrict__ out) {
  __shared__ __align__(16) unsigned short P16s[64 * 72];
  __shared__ __align__(16) float Gf[48 * 52];
  __shared__ __align__(16) unsigned short CTXs[128 * 72];
  __shared__ __align__(16) unsigned short A16s[64 * 136];
  __shared__ float biasL[SIM];
  __shared__ float rn_s[QQ];
  __shared__ float rowsumL[QQ * 9];

  const int t = threadIdx.x, bb = blockIdx.x;
  const int lane = t & 63, w = t >> 6;
  const int ml = lane & 15, kg = lane >> 4;

  // init: zero P16 (pad cols must be true zeros for MFMA), bias
  for (int idx = t; idx < 64 * 72 / 2; idx += 512) ((unsigned*)P16s)[idx] = 0;
  if (t < 256) biasL[t] = bvec[t];
  __syncthreads();
  for (int idx = t; idx < QQ * SS; idx += 512) {
    int q = idx / 36, s = idx - q * 36;
    P16s[q * 72 + s] = f2bf(attn[(size_t)bb * (QQ * SS) + idx]);
  }

  // ---- G phase: G = C.C^T, tiles (i,j) i,j<3; wave w -> tile w (+ tile 8 for w0)
  const int gi = w / 3, gj = w - gi * 3;
  f32x4 accg0 = (f32x4){0.f, 0.f, 0.f, 0.f};
  f32x4 accg1 = (f32x4){0.f, 0.f, 0.f, 0.f};
  for (int ch = 0; ch < 8; ++ch) {
    const int d0 = ch * 128;
    for (int idx = t; idx < 768; idx += 512) {
      int row = idx >> 4, c8 = idx & 15;
      u16x8 pk = (u16x8){0, 0, 0, 0, 0, 0, 0, 0};
      if (row < 36) {
        const float4* gc = (const float4*)&context[((size_t)bb * SS + row) * DD + d0 + c8 * 8];
        float4 a0 = gc[0], a1 = gc[1];
        pk[0] = f2bf(a0.x); pk[1] = f2bf(a0.y); pk[2] = f2bf(a0.z); pk[3] = f2bf(a0.w);
        pk[4] = f2bf(a1.x); pk[5] = f2bf(a1.y); pk[6] = f2bf(a1.z); pk[7] = f2bf(a1.w);
      }
      *(u16x8*)&CTXs[row * 136 + c8 * 8] = pk;
    }
    __syncthreads();
#pragma unroll
    for (int ks = 0; ks < 4; ++ks) {
      const int ko = ks * 32 + kg * 8;
      bf16x8 af = __builtin_bit_cast(bf16x8, *(const u16x8*)&CTXs[(gi * 16 + ml) * 136 + ko]);
      bf16x8 bf = __builtin_bit_cast(bf16x8, *(const u16x8*)&CTXs[(gj * 16 + ml) * 136 + ko]);
      accg0 = __builtin_amdgcn_mfma_f32_16x16x32_bf16(af, bf, accg0, 0, 0, 0);
      if (w == 0) {  // tile (2,2)
        bf16x8 cf = __builtin_bit_cast(bf16x8, *(const u16x8*)&CTXs[(32 + ml) * 136 + ko]);
        accg1 = __builtin_amdgcn_mfma_f32_16x16x32_bf16(cf, cf, accg1, 0, 0, 0);
      }
    }
    __syncthreads();
  }
#pragma unroll
  for (int ii = 0; ii < 4; ++ii)
    Gf[(gi * 16 + kg * 4 + ii) * 52 + gj * 16 + ml] = accg0[ii];
  if (w == 0) {
#pragma unroll
    for (int ii = 0; ii < 4; ++ii) Gf[(32 + kg * 4 + ii) * 52 + 32 + ml] = accg1[ii];
  }
  __syncthreads();

  // ---- QF: ||wc_q||^2 = p_q G p_q^T; 8 threads per q
  {
    const int e = t & 7, q = t >> 3;
    float preg[36];
#pragma unroll
    for (int s = 0; s < 36; ++s) preg[s] = bf2f(P16s[q * 72 + s]);
    float ssum = 0.f;
#pragma unroll
    for (int jj = 0; jj < 5; ++jj) {
      int sp = e + 8 * jj;
      if (sp < 36) {
        float tmp = 0.f;
#pragma unroll
        for (int s = 0; s < 36; ++s) tmp = fmaf(preg[s], Gf[s * 52 + sp], tmp);
        ssum = fmaf(tmp, preg[sp], ssum);
      }
    }
    ssum += __shfl_xor(ssum, 1);
    ssum += __shfl_xor(ssum, 2);
    ssum += __shfl_xor(ssum, 4);
    if (e == 0) rn_s[q] = 1.f / (sqrtf(ssum) + 1e-8f);
  }
  // zero ctxT pad cols [36,72) once (region persists; staging only writes s<36)
  {
    int r = t >> 2, cb = 36 + (t & 3) * 9;
#pragma unroll
    for (int jj = 0; jj < 9; ++jj) CTXs[r * 72 + cb + jj] = 0;
  }
  __syncthreads();

  // ---- main chunk loop
  f32x4 accs[4][2];
#pragma unroll
  for (int mt = 0; mt < 4; ++mt)
#pragma unroll
    for (int ntl = 0; ntl < 2; ++ntl) accs[mt][ntl] = (f32x4){0.f, 0.f, 0.f, 0.f};

  for (int ch = 0; ch < 8; ++ch) {
    const int d0 = ch * 128;
    // stage ctxT[d][s] (transposed, bf16)
    for (int idx = t; idx < 1152; idx += 512) {
      int s = idx >> 5, dl4 = (idx & 31) * 4;
      float4 v = *(const float4*)&context[((size_t)bb * SS + s) * DD + d0 + dl4];
      CTXs[(dl4 + 0) * 72 + s] = f2bf(v.x);
      CTXs[(dl4 + 1) * 72 + s] = f2bf(v.y);
      CTXs[(dl4 + 2) * 72 + s] = f2bf(v.z);
      CTXs[(dl4 + 3) * 72 + s] = f2bf(v.w);
    }
    __syncthreads();
    // wc = P.C : wave w owns d-cols [w*16, w*16+16)
    f32x4 aw[4];
#pragma unroll
    for (int mt = 0; mt < 4; ++mt) aw[mt] = (f32x4){0.f, 0.f, 0.f, 0.f};
#pragma unroll
    for (int ks = 0; ks < 2; ++ks) {
      const int ko = ks * 32 + kg * 8;
      bf16x8 bfr = __builtin_bit_cast(bf16x8, *(const u16x8*)&CTXs[(w * 16 + ml) * 72 + ko]);
#pragma unroll
      for (int mt = 0; mt < 4; ++mt) {
        bf16x8 af = __builtin_bit_cast(bf16x8, *(const u16x8*)&P16s[(mt * 16 + ml) * 72 + ko]);
        aw[mt] = __builtin_amdgcn_mfma_f32_16x16x32_bf16(af, bfr, aw[mt], 0, 0, 0);
      }
    }
    // A = (query - wc*rn)^2 -> A16 (bf16)
#pragma unroll
    for (int mt = 0; mt < 4; ++mt)
#pragma unroll
      for (int ii = 0; ii < 4; ++ii) {
        int q = mt * 16 + kg * 4 + ii;
        float rn = rn_s[q];
        float qv = query[((size_t)bb * QQ + q) * DD + d0 + w * 16 + ml];
        float av = qv - aw[mt][ii] * rn;
        A16s[q * 136 + w * 16 + ml] = f2bf(av * av);
      }
    __syncthreads();
    // sim GEMM: accumulate A16 . W^T; wave w owns out cols [w*32, w*32+32)
#pragma unroll
    for (int ks = 0; ks < 4; ++ks) {
      const int ko = ks * 32 + kg * 8;
      bf16x8 bfr[2];
#pragma unroll
      for (int ntl = 0; ntl < 2; ++ntl) {
        const size_t wrow = (size_t)(w * 32 + ntl * 16 + ml);
        if constexpr (USE_W16) {
          bfr[ntl] = __builtin_bit_cast(bf16x8, *(const u16x8*)&W16[wrow * DD + d0 + ko]);
        } else {
          const float4* wp = (const float4*)&Wm[wrow * DD + d0 + ko];
          float4 x = wp[0], y = wp[1];
          u16x8 pk;
          pk[0] = f2bf(x.x); pk[1] = f2bf(x.y); pk[2] = f2bf(x.z); pk[3] = f2bf(x.w);
          pk[4] = f2bf(y.x); pk[5] = f2bf(y.y); pk[6] = f2bf(y.z); pk[7] = f2bf(y.w);
          bfr[ntl] = __builtin_bit_cast(bf16x8, pk);
        }
      }
#pragma unroll
      for (int mt = 0; mt < 4; ++mt) {
        bf16x8 af = __builtin_bit_cast(bf16x8, *(const u16x8*)&A16s[(mt * 16 + ml) * 136 + ko]);
#pragma unroll
        for (int ntl = 0; ntl < 2; ++ntl)
          accs[mt][ntl] = __builtin_amdgcn_mfma_f32_16x16x32_bf16(af, bfr[ntl], accs[mt][ntl], 0, 0, 0);
      }
    }
    __syncthreads();
  }

  // ---- epilogue: +bias, l2norm over 256, store
#pragma unroll
  for (int mt = 0; mt < 4; ++mt)
#pragma unroll
    for (int ii = 0; ii < 4; ++ii) {
      int q = mt * 16 + kg * 4 + ii;
      float partial = 0.f;
#pragma unroll
      for (int ntl = 0; ntl < 2; ++ntl) {
        int col = w * 32 + ntl * 16 + ml;
        float v = accs[mt][ntl][ii] + biasL[col];
        partial = fmaf(v, v, partial);
      }
      partial += __shfl_xor(partial, 1);
      partial += __shfl_xor(partial, 2);
      partial += __shfl_xor(partial, 4);
      partial += __shfl_xor(partial, 8);
      if (ml == 0) rowsumL[q * 9 + w] = partial;
    }
  __syncthreads();
  if (t < 64) {
    float ssum = 0.f;
#pragma unroll
    for (int w2 = 0; w2 < 8; ++w2) ssum += rowsumL[t * 9 + w2];
    rn_s[t] = 1.f / (sqrtf(ssum) + 1e-8f);
  }
  __syncthreads();
#pragma unroll
  for (int mt = 0; mt < 4; ++mt)
#pragma unroll
    for (int ntl = 0; ntl < 2; ++ntl)
#pragma unroll
      for (int ii = 0; ii < 4; ++ii) {
        int q = mt * 16 + kg * 4 + ii;
        int col = w * 32 + ntl * 16 + ml;
        float v = accs[mt][ntl][ii] + biasL[col];
        out[((size_t)bb * QQ + q) * SIM + col] = v * rn_s[q];
      }
}

extern "C" void kernel_launch(void* const* d_in, const int* in_sizes, int n_in,
                              void* d_out, int out_size, void* d_ws, size_t ws_size,
                              hipStream_t stream) {
  const float* query = (const float*)d_in[0];
  const float* context = (const float*)d_in[1];
  const float* matrix = (const float*)d_in[2];
  const float* Wm = (const float*)d_in[3];
  const float* bvec = (const float*)d_in[4];
  const int* smoothp = (const int*)d_in[5];
  float* out = (float*)d_out;
  float* attn = (float*)d_ws;  // 512*64*36*4 = 4718592 B
  const size_t attnB = (size_t)BB * QQ * SS * 4;
  unsigned short* W16 = (unsigned short*)((char*)d_ws + attnB);  // 512 KB
  const bool useW16 = ws_size >= attnB + (size_t)SIM * DD * 2;

  k1_attn<<<dim3(BB), dim3(256), 0, stream>>>(query, context, matrix, smoothp, attn);
  if (useW16) {
    k0_w16<<<dim3(SIM * DD / 1024), dim3(256), 0, stream>>>(Wm, W16);
    k2_fused<true><<<dim3(BB), dim3(512), 0, stream>>>(query, context, Wm, bvec, attn, W16, out);
  } else {
    k2_fused<false><<<dim3(BB), dim3(512), 0, stream>>>(query, context, Wm, bvec, attn, W16, out);
  }
}

// Round 4
// 169.141 us; speedup vs baseline: 1.1697x; 1.1697x over previous
//
#include <hip/hip_runtime.h>
#include <hip/hip_bf16.h>

// Problem dims (fixed by reference): B=512, Q=64, S=36, D=1024, SIM=256
#define BB 512
#define QQ 64
#define SS 36
#define DD 1024
#define SIM 256

typedef unsigned short u16x8 __attribute__((ext_vector_type(8)));
typedef unsigned short u16x4 __attribute__((ext_vector_type(4)));
typedef __bf16 bf16x8 __attribute__((ext_vector_type(8)));
typedef float f32x4 __attribute__((ext_vector_type(4)));
typedef unsigned short us;

__device__ __forceinline__ us f2bf(float f) {
  unsigned u = __float_as_uint(f);
  u += 0x7FFFu + ((u >> 16) & 1u);   // round-to-nearest-even
  return (us)(u >> 16);
}
__device__ __forceinline__ float bf2f(us h) {
  return __uint_as_float(((unsigned)h) << 16);
}

// ---------------------------------------------------------------------------
// K0: one-shot W (256x1024 f32) -> bf16 row-major copy in ws. L2-resident.
// ---------------------------------------------------------------------------
__global__ __launch_bounds__(256) void k0_w16(const float* __restrict__ W,
                                              us* __restrict__ W16) {
  int i = blockIdx.x * 256 + threadIdx.x;  // 65536 float4s
  float4 v = ((const float4*)W)[i];
  ushort4 p;
  p.x = f2bf(v.x); p.y = f2bf(v.y); p.z = f2bf(v.z); p.w = f2bf(v.w);
  ((ushort4*)W16)[i] = p;
}

// ---------------------------------------------------------------------------
// K1: per-batch scores = ctx . qm^T via MFMA (HBM-bound), PLUS G = ctx.ctx^T
// on the idle MFMA pipe (waves 0-2, reusing staged ctx fragments).
// Epilogue: leaky -> l2norm(Q) -> softmax(S) -> probs bf16 to ws; G bf16 to ws.
// grid=512, block=256 (4 waves). LDS 30464B.
// ---------------------------------------------------------------------------
__global__ __launch_bounds__(256) void k1_attn(
    const float* __restrict__ query, const float* __restrict__ context,
    const float* __restrict__ matrix, const int* __restrict__ smoothp,
    us* __restrict__ attnBF, us* __restrict__ Gws) {
  __shared__ __align__(16) char smem1[30464];
  us* qmL = (us*)smem1;                // [64][136]
  us* ctxL = (us*)(smem1 + 17408);     // [48][136]
  float* sc = (float*)smem1;           // [48][68] (aliases qmL after GEMM)

  const int t = threadIdx.x;
  const int bb = blockIdx.x;
  const int lane = t & 63, w = t >> 6;
  const int ml = lane & 15, kg = lane >> 4;
  const float smf = (float)smoothp[0];

  f32x4 acc[3];
#pragma unroll
  for (int mt = 0; mt < 3; ++mt) acc[mt] = (f32x4){0.f, 0.f, 0.f, 0.f};
  f32x4 accg[3];
#pragma unroll
  for (int j = 0; j < 3; ++j) accg[j] = (f32x4){0.f, 0.f, 0.f, 0.f};

  for (int ch = 0; ch < 8; ++ch) {
    const int d0 = ch * 128;
    // stage qm = query*matrix bf16: thread -> (row, 8 consecutive d)
#pragma unroll
    for (int i = 0; i < 4; ++i) {
      int idx = t + 256 * i;
      int row = idx >> 4, c8 = idx & 15;
      const float4* gq = (const float4*)&query[((size_t)bb * QQ + row) * DD + d0 + c8 * 8];
      const float4* gm = (const float4*)&matrix[((size_t)bb * QQ + row) * DD + d0 + c8 * 8];
      float4 a0 = gq[0], a1 = gq[1], m0 = gm[0], m1 = gm[1];
      u16x8 pk;
      pk[0] = f2bf(a0.x * m0.x); pk[1] = f2bf(a0.y * m0.y);
      pk[2] = f2bf(a0.z * m0.z); pk[3] = f2bf(a0.w * m0.w);
      pk[4] = f2bf(a1.x * m1.x); pk[5] = f2bf(a1.y * m1.y);
      pk[6] = f2bf(a1.z * m1.z); pk[7] = f2bf(a1.w * m1.w);
      *(u16x8*)&qmL[row * 136 + c8 * 8] = pk;
    }
    // stage ctx bf16 (rows 36-47 zero)
#pragma unroll
    for (int i = 0; i < 3; ++i) {
      int idx = t + 256 * i;
      int row = idx >> 4, c8 = idx & 15;
      u16x8 pk = (u16x8){0, 0, 0, 0, 0, 0, 0, 0};
      if (row < 36) {
        const float4* gc = (const float4*)&context[((size_t)bb * SS + row) * DD + d0 + c8 * 8];
        float4 a0 = gc[0], a1 = gc[1];
        pk[0] = f2bf(a0.x); pk[1] = f2bf(a0.y); pk[2] = f2bf(a0.z); pk[3] = f2bf(a0.w);
        pk[4] = f2bf(a1.x); pk[5] = f2bf(a1.y); pk[6] = f2bf(a1.z); pk[7] = f2bf(a1.w);
      }
      *(u16x8*)&ctxL[row * 136 + c8 * 8] = pk;
    }
    __syncthreads();
#pragma unroll
    for (int ks = 0; ks < 4; ++ks) {
      const int ko = ks * 32 + kg * 8;
      bf16x8 bfrag = __builtin_bit_cast(bf16x8, *(const u16x8*)&qmL[(w * 16 + ml) * 136 + ko]);
      bf16x8 af0 = __builtin_bit_cast(bf16x8, *(const u16x8*)&ctxL[(0 + ml) * 136 + ko]);
      bf16x8 af1 = __builtin_bit_cast(bf16x8, *(const u16x8*)&ctxL[(16 + ml) * 136 + ko]);
      bf16x8 af2 = __builtin_bit_cast(bf16x8, *(const u16x8*)&ctxL[(32 + ml) * 136 + ko]);
      acc[0] = __builtin_amdgcn_mfma_f32_16x16x32_bf16(af0, bfrag, acc[0], 0, 0, 0);
      acc[1] = __builtin_amdgcn_mfma_f32_16x16x32_bf16(af1, bfrag, acc[1], 0, 0, 0);
      acc[2] = __builtin_amdgcn_mfma_f32_16x16x32_bf16(af2, bfrag, acc[2], 0, 0, 0);
      if (w < 3) {  // G row-block w: tiles (w, 0..2); reuse af* fragments
        bf16x8 ai = __builtin_bit_cast(bf16x8, *(const u16x8*)&ctxL[(w * 16 + ml) * 136 + ko]);
        accg[0] = __builtin_amdgcn_mfma_f32_16x16x32_bf16(ai, af0, accg[0], 0, 0, 0);
        accg[1] = __builtin_amdgcn_mfma_f32_16x16x32_bf16(ai, af1, accg[1], 0, 0, 0);
        accg[2] = __builtin_amdgcn_mfma_f32_16x16x32_bf16(ai, af2, accg[2], 0, 0, 0);
      }
    }
    __syncthreads();
  }

  // spill G (bf16) to ws: Gws[bb][48][48]
  if (w < 3) {
#pragma unroll
    for (int j = 0; j < 3; ++j)
#pragma unroll
      for (int ii = 0; ii < 4; ++ii)
        Gws[(size_t)bb * 2304 + (w * 16 + kg * 4 + ii) * 48 + j * 16 + ml] = f2bf(accg[j][ii]);
  }
  // leaky + spill scores to sc[s][q]
#pragma unroll
  for (int mt = 0; mt < 3; ++mt)
#pragma unroll
    for (int ii = 0; ii < 4; ++ii) {
      float v = acc[mt][ii];
      v = v > 0.f ? v : 0.1f * v;
      sc[(mt * 16 + kg * 4 + ii) * 68 + w * 16 + ml] = v;
    }
  __syncthreads();

  if (t < 36) {  // l2norm over q per row s
    float ssum = 0.f;
    for (int qi = 0; qi < 64; ++qi) { float v = sc[t * 68 + qi]; ssum = fmaf(v, v, ssum); }
    float rn = 1.f / (sqrtf(ssum) + 1e-8f);
    for (int qi = 0; qi < 64; ++qi) sc[t * 68 + qi] *= rn;
  }
  __syncthreads();

  if (t < 64) {  // softmax over s per column q -> probs bf16 to ws
    float mx = -1e30f;
    for (int s2 = 0; s2 < 36; ++s2) mx = fmaxf(mx, sc[s2 * 68 + t]);
    float sum = 0.f;
    float ev[36];
    for (int s2 = 0; s2 < 36; ++s2) {
      float e = __expf((sc[s2 * 68 + t] - mx) * smf);
      ev[s2] = e;
      sum += e;
    }
    float rs = 1.f / sum;
    size_t base = (size_t)bb * (QQ * SS) + t * SS;
#pragma unroll
    for (int s2 = 0; s2 < 36; ++s2) attnBF[base + s2] = f2bf(ev[s2] * rs);
  }
}

// ---------------------------------------------------------------------------
// K2 (lean single pass): per-batch, 512 thr (8 waves), 49.7KB LDS.
// init: P16 (probs bf16), G -> V = P.G^T (MFMA) -> rn_q = 1/(sqrt(p.V)+eps)
// per 128-d chunk: stage ctxT[128][76] (transposed reads, b64 writes) ->
//   wc = P.C (MFMA) -> A = (q - wc*rn)^2 bf16 -> sim GEMM accumulate A.W^T.
// epilogue: +bias, l2norm over 256, store. All 8 waves active in every phase.
// LDS: P16[64][72]@0 | ctxT[128][76]@9216 | A16[64][136]@28672 (G aliases)
//      | bias@46080 | rnL@47104 | rsum@47360 -> 49664 B total.
// ---------------------------------------------------------------------------
template <bool USE_W16>
__global__ __launch_bounds__(512, 4) void k2_fused(
    const float* __restrict__ query, const float* __restrict__ context,
    const float* __restrict__ Wm, const float* __restrict__ bvec,
    const us* __restrict__ attnBF, const us* __restrict__ Gws,
    const us* __restrict__ W16, float* __restrict__ out) {
  __shared__ __align__(16) char smem[49664];
  us* P16s = (us*)smem;                  // [64][72]
  us* ctxTs = (us*)(smem + 9216);        // [128][76], row stride 152B
  us* A16s = (us*)(smem + 28672);        // [64][136]
  us* Gf16L = (us*)(smem + 28672);       // [48][72] (aliases A16s, init only)
  float* biasL = (float*)(smem + 46080); // [256]
  float* rnL = (float*)(smem + 47104);   // [64]
  float* rsum = (float*)(smem + 47360);  // [64*9]

  const int t = threadIdx.x, bb = blockIdx.x;
  const int lane = t & 63, w = t >> 6;
  const int ml = lane & 15, kg = lane >> 4;

  // ---- init: zero pads
  for (int idx = t; idx < 2304; idx += 512) ((unsigned*)P16s)[idx] = 0;
  for (int idx = t; idx < 1728; idx += 512) ((unsigned*)Gf16L)[idx] = 0;
  for (int idx = t; idx < 1792; idx += 512) {  // ctxT cols 36..63 zero (persist)
    int r = idx / 14, c = idx - r * 14;
    *(unsigned*)&ctxTs[r * 76 + 36 + c * 2] = 0;
  }
  if (t < 256) biasL[t] = bvec[t];
  __syncthreads();
  // fill P16 (bf16 copy) and Gf16L
  for (int idx = t; idx < 1152; idx += 512) {
    int q = idx / 18, c2 = idx - q * 18;
    *(unsigned*)&P16s[q * 72 + c2 * 2] = ((const unsigned*)attnBF)[(size_t)bb * 1152 + idx];
  }
  for (int idx = t; idx < 1152; idx += 512) {
    int r = idx / 24, c2 = idx - r * 24;
    *(unsigned*)&Gf16L[r * 72 + c2 * 2] = ((const unsigned*)Gws)[(size_t)bb * 1152 + idx];
  }
  __syncthreads();

  // ---- V = P.G^T (G symmetric), then ||wc_q||^2 = sum_sp p[q][sp]*V[q][sp]
  if (w < 3) {
    f32x4 accv[4];
#pragma unroll
    for (int mt = 0; mt < 4; ++mt) accv[mt] = (f32x4){0.f, 0.f, 0.f, 0.f};
#pragma unroll
    for (int ks = 0; ks < 2; ++ks) {
      const int ko = ks * 32 + kg * 8;
      bf16x8 gfr = __builtin_bit_cast(bf16x8, *(const u16x8*)&Gf16L[(w * 16 + ml) * 72 + ko]);
#pragma unroll
      for (int mt = 0; mt < 4; ++mt) {
        bf16x8 pf = __builtin_bit_cast(bf16x8, *(const u16x8*)&P16s[(mt * 16 + ml) * 72 + ko]);
        accv[mt] = __builtin_amdgcn_mfma_f32_16x16x32_bf16(pf, gfr, accv[mt], 0, 0, 0);
      }
    }
#pragma unroll
    for (int mt = 0; mt < 4; ++mt)
#pragma unroll
      for (int ii = 0; ii < 4; ++ii) {
        int q = mt * 16 + kg * 4 + ii;
        float vv = accv[mt][ii] * bf2f(P16s[q * 72 + w * 16 + ml]);
        vv += __shfl_xor(vv, 1);
        vv += __shfl_xor(vv, 2);
        vv += __shfl_xor(vv, 4);
        vv += __shfl_xor(vv, 8);
        if (ml == 0) rsum[q * 4 + w] = vv;
      }
  }
  __syncthreads();
  if (t < 64) {
    float s2 = rsum[t * 4] + rsum[t * 4 + 1] + rsum[t * 4 + 2];
    rnL[t] = 1.f / (sqrtf(s2) + 1e-8f);
  }

  // ---- main chunk loop
  f32x4 accs[4][2];
#pragma unroll
  for (int mt = 0; mt < 4; ++mt)
#pragma unroll
    for (int ntl = 0; ntl < 2; ++ntl) accs[mt][ntl] = (f32x4){0.f, 0.f, 0.f, 0.f};

  for (int ch = 0; ch < 8; ++ch) {
    const int d0 = ch * 128;
    // (a) stage ctxT: transposed global reads (coalesced rows), b64 LDS writes
    for (int idx = t; idx < 1152; idx += 512) {
      int d = idx & 127, s0 = (idx >> 7) * 4;
      const float* cp = &context[((size_t)bb * SS + s0) * DD + d0 + d];
      u16x4 pk;
      pk[0] = f2bf(cp[0]);
      pk[1] = f2bf(cp[DD]);
      pk[2] = f2bf(cp[2 * DD]);
      pk[3] = f2bf(cp[3 * DD]);
      *(u16x4*)&ctxTs[d * 76 + s0] = pk;
    }
    __syncthreads();  // (b)
    // (c) wc = P.C : wave w owns d-cols [w*16, w*16+16)
    f32x4 aw[4];
#pragma unroll
    for (int mt = 0; mt < 4; ++mt) aw[mt] = (f32x4){0.f, 0.f, 0.f, 0.f};
#pragma unroll
    for (int ks = 0; ks < 2; ++ks) {
      const int ko = ks * 32 + kg * 8;
      u16x4 blo = *(const u16x4*)&ctxTs[(w * 16 + ml) * 76 + ko];
      u16x4 bhi = *(const u16x4*)&ctxTs[(w * 16 + ml) * 76 + ko + 4];
      bf16x8 bfr = __builtin_bit_cast(bf16x8, __builtin_shufflevector(blo, bhi, 0, 1, 2, 3, 4, 5, 6, 7));
#pragma unroll
      for (int mt = 0; mt < 4; ++mt) {
        bf16x8 af = __builtin_bit_cast(bf16x8, *(const u16x8*)&P16s[(mt * 16 + ml) * 72 + ko]);
        aw[mt] = __builtin_amdgcn_mfma_f32_16x16x32_bf16(af, bfr, aw[mt], 0, 0, 0);
      }
    }
    // (d) A = (query - wc*rn)^2 -> A16 bf16
#pragma unroll
    for (int mt = 0; mt < 4; ++mt)
#pragma unroll
      for (int ii = 0; ii < 4; ++ii) {
        int q = mt * 16 + kg * 4 + ii;
        float qv = query[((size_t)bb * QQ + q) * DD + d0 + w * 16 + ml];
        float av = qv - aw[mt][ii] * rnL[q];
        A16s[q * 136 + w * 16 + ml] = f2bf(av * av);
      }
    __syncthreads();  // (e)
    // (f) sim GEMM: wave w owns out cols [w*32, w*32+32)
#pragma unroll
    for (int ks = 0; ks < 4; ++ks) {
      const int ko = ks * 32 + kg * 8;
      bf16x8 bfr[2];
#pragma unroll
      for (int ntl = 0; ntl < 2; ++ntl) {
        const size_t wrow = (size_t)(w * 32 + ntl * 16 + ml);
        if constexpr (USE_W16) {
          bfr[ntl] = __builtin_bit_cast(bf16x8, *(const u16x8*)&W16[wrow * DD + d0 + ko]);
        } else {
          const float4* wp = (const float4*)&Wm[wrow * DD + d0 + ko];
          float4 x = wp[0], y = wp[1];
          u16x8 pk;
          pk[0] = f2bf(x.x); pk[1] = f2bf(x.y); pk[2] = f2bf(x.z); pk[3] = f2bf(x.w);
          pk[4] = f2bf(y.x); pk[5] = f2bf(y.y); pk[6] = f2bf(y.z); pk[7] = f2bf(y.w);
          bfr[ntl] = __builtin_bit_cast(bf16x8, pk);
        }
      }
#pragma unroll
      for (int mt = 0; mt < 4; ++mt) {
        bf16x8 af = __builtin_bit_cast(bf16x8, *(const u16x8*)&A16s[(mt * 16 + ml) * 136 + ko]);
#pragma unroll
        for (int ntl = 0; ntl < 2; ++ntl)
          accs[mt][ntl] = __builtin_amdgcn_mfma_f32_16x16x32_bf16(af, bfr[ntl], accs[mt][ntl], 0, 0, 0);
      }
    }
    __syncthreads();  // (g) — protects ctxT(c-reads) vs next (a), A16(f-reads) vs next (d)
  }

  // ---- epilogue: +bias, l2norm over 256, store
#pragma unroll
  for (int mt = 0; mt < 4; ++mt)
#pragma unroll
    for (int ii = 0; ii < 4; ++ii) {
      int q = mt * 16 + kg * 4 + ii;
      float partial = 0.f;
#pragma unroll
      for (int ntl = 0; ntl < 2; ++ntl) {
        int col = w * 32 + ntl * 16 + ml;
        float v = accs[mt][ntl][ii] + biasL[col];
        partial = fmaf(v, v, partial);
      }
      partial += __shfl_xor(partial, 1);
      partial += __shfl_xor(partial, 2);
      partial += __shfl_xor(partial, 4);
      partial += __shfl_xor(partial, 8);
      if (ml == 0) rsum[q * 9 + w] = partial;
    }
  __syncthreads();
  if (t < 64) {
    float ssum = 0.f;
#pragma unroll
    for (int w2 = 0; w2 < 8; ++w2) ssum += rsum[t * 9 + w2];
    rnL[t] = 1.f / (sqrtf(ssum) + 1e-8f);
  }
  __syncthreads();
#pragma unroll
  for (int mt = 0; mt < 4; ++mt)
#pragma unroll
    for (int ntl = 0; ntl < 2; ++ntl)
#pragma unroll
      for (int ii = 0; ii < 4; ++ii) {
        int q = mt * 16 + kg * 4 + ii;
        int col = w * 32 + ntl * 16 + ml;
        float v = accs[mt][ntl][ii] + biasL[col];
        out[((size_t)bb * QQ + q) * SIM + col] = v * rnL[q];
      }
}

extern "C" void kernel_launch(void* const* d_in, const int* in_sizes, int n_in,
                              void* d_out, int out_size, void* d_ws, size_t ws_size,
                              hipStream_t stream) {
  const float* query = (const float*)d_in[0];
  const float* context = (const float*)d_in[1];
  const float* matrix = (const float*)d_in[2];
  const float* Wm = (const float*)d_in[3];
  const float* bvec = (const float*)d_in[4];
  const int* smoothp = (const int*)d_in[5];
  float* out = (float*)d_out;

  // ws layout: [attn bf16: 2359296][G bf16: 2359296][W16 optional: 524288]
  // attn+G = 4718592 B == the round-1-proven ws requirement.
  const size_t attnB = (size_t)BB * QQ * SS * 2;
  us* attnBF = (us*)d_ws;
  us* Gws = (us*)((char*)d_ws + attnB);
  us* W16 = (us*)((char*)d_ws + 2 * attnB);
  const bool useW16 = ws_size >= 2 * attnB + (size_t)SIM * DD * 2;

  k1_attn<<<dim3(BB), dim3(256), 0, stream>>>(query, context, matrix, smoothp, attnBF, Gws);
  if (useW16) {
    k0_w16<<<dim3(SIM * DD / 1024), dim3(256), 0, stream>>>(Wm, W16);
    k2_fused<true><<<dim3(BB), dim3(512), 0, stream>>>(query, context, Wm, bvec, attnBF, Gws, W16, out);
  } else {
    k2_fused<false><<<dim3(BB), dim3(512), 0, stream>>>(query, context, Wm, bvec, attnBF, Gws, W16, out);
  }
}

// Round 5
// 162.052 us; speedup vs baseline: 1.2208x; 1.0437x over previous
//
#include <hip/hip_runtime.h>
#include <hip/hip_bf16.h>

// Problem dims (fixed by reference): B=512, Q=64, S=36, D=1024, SIM=256
#define BB 512
#define QQ 64
#define SS 36
#define DD 1024
#define SIM 256

typedef unsigned short u16x8 __attribute__((ext_vector_type(8)));
typedef unsigned short u16x4 __attribute__((ext_vector_type(4)));
typedef __bf16 bf16x8 __attribute__((ext_vector_type(8)));
typedef float f32x4 __attribute__((ext_vector_type(4)));
typedef unsigned short us;

__device__ __forceinline__ us f2bf(float f) {
  unsigned u = __float_as_uint(f);
  u += 0x7FFFu + ((u >> 16) & 1u);   // round-to-nearest-even
  return (us)(u >> 16);
}
__device__ __forceinline__ float bf2f(us h) {
  return __uint_as_float(((unsigned)h) << 16);
}

// ---------------------------------------------------------------------------
// K0: one-shot W (256x1024 f32) -> bf16 row-major copy in ws. L2-resident.
// ---------------------------------------------------------------------------
__global__ __launch_bounds__(256) void k0_w16(const float* __restrict__ W,
                                              us* __restrict__ W16) {
  int i = blockIdx.x * 256 + threadIdx.x;  // 65536 float4s
  float4 v = ((const float4*)W)[i];
  ushort4 p;
  p.x = f2bf(v.x); p.y = f2bf(v.y); p.z = f2bf(v.z); p.w = f2bf(v.w);
  ((ushort4*)W16)[i] = p;
}

// ---------------------------------------------------------------------------
// K1, grid = 1024:
//  blocks [0,512):   scores = ctx . qm^T via MFMA (round-3 hot loop, proven),
//                    leaky -> l2norm(Q) -> softmax(S) -> probs bf16 to ws.
//  blocks [512,1024): G = ctx . ctx^T (48x48 pad) for batch bb-512 -> bf16 ws.
//                    Memory-light; overlaps with the heavy blocks.
// block = 256 (4 waves). LDS 30464B (main) / 13056B used (G path).
// ---------------------------------------------------------------------------
__global__ __launch_bounds__(256) void k1_attn(
    const float* __restrict__ query, const float* __restrict__ context,
    const float* __restrict__ matrix, const int* __restrict__ smoothp,
    us* __restrict__ attnBF, us* __restrict__ Gws) {
  __shared__ __align__(16) char smem1[30464];

  const int t = threadIdx.x;
  const int lane = t & 63, w = t >> 6;
  const int ml = lane & 15, kg = lane >> 4;

  if (blockIdx.x >= BB) {
    // ---- G path ----
    const int bb = blockIdx.x - BB;
    us* ctxL = (us*)smem1;  // [48][136]
    f32x4 accg[3];
#pragma unroll
    for (int j = 0; j < 3; ++j) accg[j] = (f32x4){0.f, 0.f, 0.f, 0.f};

    for (int ch = 0; ch < 8; ++ch) {
      const int d0 = ch * 128;
#pragma unroll
      for (int i = 0; i < 3; ++i) {
        int idx = t + 256 * i;
        int row = idx >> 4, c8 = idx & 15;
        u16x8 pk = (u16x8){0, 0, 0, 0, 0, 0, 0, 0};
        if (row < 36) {
          const float4* gc = (const float4*)&context[((size_t)bb * SS + row) * DD + d0 + c8 * 8];
          float4 a0 = gc[0], a1 = gc[1];
          pk[0] = f2bf(a0.x); pk[1] = f2bf(a0.y); pk[2] = f2bf(a0.z); pk[3] = f2bf(a0.w);
          pk[4] = f2bf(a1.x); pk[5] = f2bf(a1.y); pk[6] = f2bf(a1.z); pk[7] = f2bf(a1.w);
        }
        *(u16x8*)&ctxL[row * 136 + c8 * 8] = pk;
      }
      __syncthreads();
      if (w < 3) {  // wave w -> G row-block w, tiles (w, 0..2)
#pragma unroll
        for (int ks = 0; ks < 4; ++ks) {
          const int ko = ks * 32 + kg * 8;
          bf16x8 ai = __builtin_bit_cast(bf16x8, *(const u16x8*)&ctxL[(w * 16 + ml) * 136 + ko]);
#pragma unroll
          for (int j = 0; j < 3; ++j) {
            bf16x8 af = __builtin_bit_cast(bf16x8, *(const u16x8*)&ctxL[(j * 16 + ml) * 136 + ko]);
            accg[j] = __builtin_amdgcn_mfma_f32_16x16x32_bf16(ai, af, accg[j], 0, 0, 0);
          }
        }
      }
      __syncthreads();
    }
    if (w < 3) {
#pragma unroll
      for (int j = 0; j < 3; ++j)
#pragma unroll
        for (int ii = 0; ii < 4; ++ii)
          Gws[(size_t)bb * 2304 + (w * 16 + kg * 4 + ii) * 48 + j * 16 + ml] = f2bf(accg[j][ii]);
    }
    return;
  }

  // ---- main path (round-3 structure) ----
  const int bb = blockIdx.x;
  us* qmL = (us*)smem1;                // [64][136]
  us* ctxL = (us*)(smem1 + 17408);     // [48][136]
  float* sc = (float*)smem1;           // [48][68] (aliases qmL after GEMM)
  const float smf = (float)smoothp[0];

  f32x4 acc[3];
#pragma unroll
  for (int mt = 0; mt < 3; ++mt) acc[mt] = (f32x4){0.f, 0.f, 0.f, 0.f};

  for (int ch = 0; ch < 8; ++ch) {
    const int d0 = ch * 128;
#pragma unroll
    for (int i = 0; i < 4; ++i) {
      int idx = t + 256 * i;
      int row = idx >> 4, c8 = idx & 15;
      const float4* gq = (const float4*)&query[((size_t)bb * QQ + row) * DD + d0 + c8 * 8];
      const float4* gm = (const float4*)&matrix[((size_t)bb * QQ + row) * DD + d0 + c8 * 8];
      float4 a0 = gq[0], a1 = gq[1], m0 = gm[0], m1 = gm[1];
      u16x8 pk;
      pk[0] = f2bf(a0.x * m0.x); pk[1] = f2bf(a0.y * m0.y);
      pk[2] = f2bf(a0.z * m0.z); pk[3] = f2bf(a0.w * m0.w);
      pk[4] = f2bf(a1.x * m1.x); pk[5] = f2bf(a1.y * m1.y);
      pk[6] = f2bf(a1.z * m1.z); pk[7] = f2bf(a1.w * m1.w);
      *(u16x8*)&qmL[row * 136 + c8 * 8] = pk;
    }
#pragma unroll
    for (int i = 0; i < 3; ++i) {
      int idx = t + 256 * i;
      int row = idx >> 4, c8 = idx & 15;
      u16x8 pk = (u16x8){0, 0, 0, 0, 0, 0, 0, 0};
      if (row < 36) {
        const float4* gc = (const float4*)&context[((size_t)bb * SS + row) * DD + d0 + c8 * 8];
        float4 a0 = gc[0], a1 = gc[1];
        pk[0] = f2bf(a0.x); pk[1] = f2bf(a0.y); pk[2] = f2bf(a0.z); pk[3] = f2bf(a0.w);
        pk[4] = f2bf(a1.x); pk[5] = f2bf(a1.y); pk[6] = f2bf(a1.z); pk[7] = f2bf(a1.w);
      }
      *(u16x8*)&ctxL[row * 136 + c8 * 8] = pk;
    }
    __syncthreads();
#pragma unroll
    for (int ks = 0; ks < 4; ++ks) {
      const int ko = ks * 32 + kg * 8;
      bf16x8 bfrag = __builtin_bit_cast(bf16x8, *(const u16x8*)&qmL[(w * 16 + ml) * 136 + ko]);
#pragma unroll
      for (int mt = 0; mt < 3; ++mt) {
        bf16x8 afrag =
            __builtin_bit_cast(bf16x8, *(const u16x8*)&ctxL[(mt * 16 + ml) * 136 + ko]);
        acc[mt] = __builtin_amdgcn_mfma_f32_16x16x32_bf16(afrag, bfrag, acc[mt], 0, 0, 0);
      }
    }
    __syncthreads();
  }

  // leaky + spill scores to sc[s][q]
#pragma unroll
  for (int mt = 0; mt < 3; ++mt)
#pragma unroll
    for (int ii = 0; ii < 4; ++ii) {
      float v = acc[mt][ii];
      v = v > 0.f ? v : 0.1f * v;
      sc[(mt * 16 + kg * 4 + ii) * 68 + w * 16 + ml] = v;
    }
  __syncthreads();

  if (t < 36) {  // l2norm over q per row s
    float ssum = 0.f;
    for (int qi = 0; qi < 64; ++qi) { float v = sc[t * 68 + qi]; ssum = fmaf(v, v, ssum); }
    float rn = 1.f / (sqrtf(ssum) + 1e-8f);
    for (int qi = 0; qi < 64; ++qi) sc[t * 68 + qi] *= rn;
  }
  __syncthreads();

  if (t < 64) {  // softmax over s per column q -> probs bf16 to ws
    float mx = -1e30f;
    for (int s2 = 0; s2 < 36; ++s2) mx = fmaxf(mx, sc[s2 * 68 + t]);
    float sum = 0.f;
    float ev[36];
    for (int s2 = 0; s2 < 36; ++s2) {
      float e = __expf((sc[s2 * 68 + t] - mx) * smf);
      ev[s2] = e;
      sum += e;
    }
    float rs = 1.f / sum;
    size_t base = (size_t)bb * (QQ * SS) + t * SS;
#pragma unroll
    for (int s2 = 0; s2 < 36; s2 += 2) {
      ushort2 p;
      p.x = f2bf(ev[s2] * rs);
      p.y = f2bf(ev[s2 + 1] * rs);
      *(ushort2*)&attnBF[base + s2] = p;
    }
  }
}

// ---------------------------------------------------------------------------
// K2 (unchanged from round 4, proven ~49us): per-batch, 512 thr, 49.7KB LDS.
// init: P16 (probs bf16), G -> V = P.G^T (MFMA) -> rn_q = 1/(sqrt(p.V)+eps)
// per 128-d chunk: stage ctxT[128][76] -> wc = P.C (MFMA) -> A=(q-wc*rn)^2
// bf16 -> sim GEMM accumulate A.W^T. epilogue: +bias, l2norm(256), store.
// ---------------------------------------------------------------------------
template <bool USE_W16>
__global__ __launch_bounds__(512, 4) void k2_fused(
    const float* __restrict__ query, const float* __restrict__ context,
    const float* __restrict__ Wm, const float* __restrict__ bvec,
    const us* __restrict__ attnBF, const us* __restrict__ Gws,
    const us* __restrict__ W16, float* __restrict__ out) {
  __shared__ __align__(16) char smem[49664];
  us* P16s = (us*)smem;                  // [64][72]
  us* ctxTs = (us*)(smem + 9216);        // [128][76], row stride 152B
  us* A16s = (us*)(smem + 28672);        // [64][136]
  us* Gf16L = (us*)(smem + 28672);       // [48][72] (aliases A16s, init only)
  float* biasL = (float*)(smem + 46080); // [256]
  float* rnL = (float*)(smem + 47104);   // [64]
  float* rsum = (float*)(smem + 47360);  // [64*9]

  const int t = threadIdx.x, bb = blockIdx.x;
  const int lane = t & 63, w = t >> 6;
  const int ml = lane & 15, kg = lane >> 4;

  // ---- init: zero pads
  for (int idx = t; idx < 2304; idx += 512) ((unsigned*)P16s)[idx] = 0;
  for (int idx = t; idx < 1728; idx += 512) ((unsigned*)Gf16L)[idx] = 0;
  for (int idx = t; idx < 1792; idx += 512) {  // ctxT cols 36..63 zero (persist)
    int r = idx / 14, c = idx - r * 14;
    *(unsigned*)&ctxTs[r * 76 + 36 + c * 2] = 0;
  }
  if (t < 256) biasL[t] = bvec[t];
  __syncthreads();
  // fill P16 (bf16 copy) and Gf16L
  for (int idx = t; idx < 1152; idx += 512) {
    int q = idx / 18, c2 = idx - q * 18;
    *(unsigned*)&P16s[q * 72 + c2 * 2] = ((const unsigned*)attnBF)[(size_t)bb * 1152 + idx];
  }
  for (int idx = t; idx < 1152; idx += 512) {
    int r = idx / 24, c2 = idx - r * 24;
    *(unsigned*)&Gf16L[r * 72 + c2 * 2] = ((const unsigned*)Gws)[(size_t)bb * 1152 + idx];
  }
  __syncthreads();

  // ---- V = P.G^T (G symmetric), then ||wc_q||^2 = sum_sp p[q][sp]*V[q][sp]
  if (w < 3) {
    f32x4 accv[4];
#pragma unroll
    for (int mt = 0; mt < 4; ++mt) accv[mt] = (f32x4){0.f, 0.f, 0.f, 0.f};
#pragma unroll
    for (int ks = 0; ks < 2; ++ks) {
      const int ko = ks * 32 + kg * 8;
      bf16x8 gfr = __builtin_bit_cast(bf16x8, *(const u16x8*)&Gf16L[(w * 16 + ml) * 72 + ko]);
#pragma unroll
      for (int mt = 0; mt < 4; ++mt) {
        bf16x8 pf = __builtin_bit_cast(bf16x8, *(const u16x8*)&P16s[(mt * 16 + ml) * 72 + ko]);
        accv[mt] = __builtin_amdgcn_mfma_f32_16x16x32_bf16(pf, gfr, accv[mt], 0, 0, 0);
      }
    }
#pragma unroll
    for (int mt = 0; mt < 4; ++mt)
#pragma unroll
      for (int ii = 0; ii < 4; ++ii) {
        int q = mt * 16 + kg * 4 + ii;
        float vv = accv[mt][ii] * bf2f(P16s[q * 72 + w * 16 + ml]);
        vv += __shfl_xor(vv, 1);
        vv += __shfl_xor(vv, 2);
        vv += __shfl_xor(vv, 4);
        vv += __shfl_xor(vv, 8);
        if (ml == 0) rsum[q * 4 + w] = vv;
      }
  }
  __syncthreads();
  if (t < 64) {
    float s2 = rsum[t * 4] + rsum[t * 4 + 1] + rsum[t * 4 + 2];
    rnL[t] = 1.f / (sqrtf(s2) + 1e-8f);
  }

  // ---- main chunk loop
  f32x4 accs[4][2];
#pragma unroll
  for (int mt = 0; mt < 4; ++mt)
#pragma unroll
    for (int ntl = 0; ntl < 2; ++ntl) accs[mt][ntl] = (f32x4){0.f, 0.f, 0.f, 0.f};

  for (int ch = 0; ch < 8; ++ch) {
    const int d0 = ch * 128;
    // (a) stage ctxT: transposed global reads (coalesced rows), b64 LDS writes
    for (int idx = t; idx < 1152; idx += 512) {
      int d = idx & 127, s0 = (idx >> 7) * 4;
      const float* cp = &context[((size_t)bb * SS + s0) * DD + d0 + d];
      u16x4 pk;
      pk[0] = f2bf(cp[0]);
      pk[1] = f2bf(cp[DD]);
      pk[2] = f2bf(cp[2 * DD]);
      pk[3] = f2bf(cp[3 * DD]);
      *(u16x4*)&ctxTs[d * 76 + s0] = pk;
    }
    __syncthreads();  // (b)
    // (c) wc = P.C : wave w owns d-cols [w*16, w*16+16)
    f32x4 aw[4];
#pragma unroll
    for (int mt = 0; mt < 4; ++mt) aw[mt] = (f32x4){0.f, 0.f, 0.f, 0.f};
#pragma unroll
    for (int ks = 0; ks < 2; ++ks) {
      const int ko = ks * 32 + kg * 8;
      u16x4 blo = *(const u16x4*)&ctxTs[(w * 16 + ml) * 76 + ko];
      u16x4 bhi = *(const u16x4*)&ctxTs[(w * 16 + ml) * 76 + ko + 4];
      bf16x8 bfr = __builtin_bit_cast(bf16x8, __builtin_shufflevector(blo, bhi, 0, 1, 2, 3, 4, 5, 6, 7));
#pragma unroll
      for (int mt = 0; mt < 4; ++mt) {
        bf16x8 af = __builtin_bit_cast(bf16x8, *(const u16x8*)&P16s[(mt * 16 + ml) * 72 + ko]);
        aw[mt] = __builtin_amdgcn_mfma_f32_16x16x32_bf16(af, bfr, aw[mt], 0, 0, 0);
      }
    }
    // (d) A = (query - wc*rn)^2 -> A16 bf16
#pragma unroll
    for (int mt = 0; mt < 4; ++mt)
#pragma unroll
      for (int ii = 0; ii < 4; ++ii) {
        int q = mt * 16 + kg * 4 + ii;
        float qv = query[((size_t)bb * QQ + q) * DD + d0 + w * 16 + ml];
        float av = qv - aw[mt][ii] * rnL[q];
        A16s[q * 136 + w * 16 + ml] = f2bf(av * av);
      }
    __syncthreads();  // (e)
    // (f) sim GEMM: wave w owns out cols [w*32, w*32+32)
#pragma unroll
    for (int ks = 0; ks < 4; ++ks) {
      const int ko = ks * 32 + kg * 8;
      bf16x8 bfr[2];
#pragma unroll
      for (int ntl = 0; ntl < 2; ++ntl) {
        const size_t wrow = (size_t)(w * 32 + ntl * 16 + ml);
        if constexpr (USE_W16) {
          bfr[ntl] = __builtin_bit_cast(bf16x8, *(const u16x8*)&W16[wrow * DD + d0 + ko]);
        } else {
          const float4* wp = (const float4*)&Wm[wrow * DD + d0 + ko];
          float4 x = wp[0], y = wp[1];
          u16x8 pk;
          pk[0] = f2bf(x.x); pk[1] = f2bf(x.y); pk[2] = f2bf(x.z); pk[3] = f2bf(x.w);
          pk[4] = f2bf(y.x); pk[5] = f2bf(y.y); pk[6] = f2bf(y.z); pk[7] = f2bf(y.w);
          bfr[ntl] = __builtin_bit_cast(bf16x8, pk);
        }
      }
#pragma unroll
      for (int mt = 0; mt < 4; ++mt) {
        bf16x8 af = __builtin_bit_cast(bf16x8, *(const u16x8*)&A16s[(mt * 16 + ml) * 136 + ko]);
#pragma unroll
        for (int ntl = 0; ntl < 2; ++ntl)
          accs[mt][ntl] = __builtin_amdgcn_mfma_f32_16x16x32_bf16(af, bfr[ntl], accs[mt][ntl], 0, 0, 0);
      }
    }
    __syncthreads();  // (g)
  }

  // ---- epilogue: +bias, l2norm over 256, store
#pragma unroll
  for (int mt = 0; mt < 4; ++mt)
#pragma unroll
    for (int ii = 0; ii < 4; ++ii) {
      int q = mt * 16 + kg * 4 + ii;
      float partial = 0.f;
#pragma unroll
      for (int ntl = 0; ntl < 2; ++ntl) {
        int col = w * 32 + ntl * 16 + ml;
        float v = accs[mt][ntl][ii] + biasL[col];
        partial = fmaf(v, v, partial);
      }
      partial += __shfl_xor(partial, 1);
      partial += __shfl_xor(partial, 2);
      partial += __shfl_xor(partial, 4);
      partial += __shfl_xor(partial, 8);
      if (ml == 0) rsum[q * 9 + w] = partial;
    }
  __syncthreads();
  if (t < 64) {
    float ssum = 0.f;
#pragma unroll
    for (int w2 = 0; w2 < 8; ++w2) ssum += rsum[t * 9 + w2];
    rnL[t] = 1.f / (sqrtf(ssum) + 1e-8f);
  }
  __syncthreads();
#pragma unroll
  for (int mt = 0; mt < 4; ++mt)
#pragma unroll
    for (int ntl = 0; ntl < 2; ++ntl)
#pragma unroll
      for (int ii = 0; ii < 4; ++ii) {
        int q = mt * 16 + kg * 4 + ii;
        int col = w * 32 + ntl * 16 + ml;
        float v = accs[mt][ntl][ii] + biasL[col];
        out[((size_t)bb * QQ + q) * SIM + col] = v * rnL[q];
      }
}

extern "C" void kernel_launch(void* const* d_in, const int* in_sizes, int n_in,
                              void* d_out, int out_size, void* d_ws, size_t ws_size,
                              hipStream_t stream) {
  const float* query = (const float*)d_in[0];
  const float* context = (const float*)d_in[1];
  const float* matrix = (const float*)d_in[2];
  const float* Wm = (const float*)d_in[3];
  const float* bvec = (const float*)d_in[4];
  const int* smoothp = (const int*)d_in[5];
  float* out = (float*)d_out;

  // ws layout: [attn bf16: 2359296][G bf16: 2359296][W16 optional: 524288]
  const size_t attnB = (size_t)BB * QQ * SS * 2;
  us* attnBF = (us*)d_ws;
  us* Gws = (us*)((char*)d_ws + attnB);
  us* W16 = (us*)((char*)d_ws + 2 * attnB);
  const bool useW16 = ws_size >= 2 * attnB + (size_t)SIM * DD * 2;

  k1_attn<<<dim3(2 * BB), dim3(256), 0, stream>>>(query, context, matrix, smoothp, attnBF, Gws);
  if (useW16) {
    k0_w16<<<dim3(SIM * DD / 1024), dim3(256), 0, stream>>>(Wm, W16);
    k2_fused<true><<<dim3(BB), dim3(512), 0, stream>>>(query, context, Wm, bvec, attnBF, Gws, W16, out);
  } else {
    k2_fused<false><<<dim3(BB), dim3(512), 0, stream>>>(query, context, Wm, bvec, attnBF, Gws, W16, out);
  }
}